// Round 4
// baseline (2873.906 us; speedup 1.0000x reference)
//
#include <hip/hip_runtime.h>
#include <hip/hip_bf16.h>
#include <math.h>
#include <stdint.h>

// Problem constants
#define T_TOK 4096
#define H_DIM 2880
#define E_NUM 16
#define ALPHA 1.702f
#define EPS_RMS 1e-5f

// GEMM tiling: BM=192 (4 waves x 3 m-frags), BN=192, BK=32.
// 3-buffer LDS pipeline, prefetch depth 2, 1 barrier / K-step, no vmcnt(0) in loop.
#define PADM 192
#define BK 32
#define NK (H_DIM / BK)       // 90 (even)
#define MAX_RT 104
#define NCT1 30               // gemm1 col tiles of 96 (+96 lin)
#define NCT2 15               // gemm2 col tiles of 192
#define G1 (MAX_RT * NCT1)    // 3120 (div 8)
#define G2 (MAX_RT * NCT2)    // 1560 (div 8)
#define ABUF 12288            // A region per buffer: 192 rows x 64 B
#define BBUF 12288            // B region per buffer
#define BOFF 36864            // B buffers base (3 x ABUF)

typedef __attribute__((ext_vector_type(8))) short short8;
typedef __attribute__((ext_vector_type(4))) float f32x4;

__device__ __forceinline__ unsigned short f2bf(float f) {
  unsigned u = __float_as_uint(f);
  return (unsigned short)((u + 0x7fffu + ((u >> 16) & 1u)) >> 16);
}
__device__ __forceinline__ unsigned pk2(float a, float b) {
  return (unsigned)f2bf(a) | ((unsigned)f2bf(b) << 16);
}
__device__ __forceinline__ void gl_lds16(const void* g, unsigned char* lds_dst) {
  __builtin_amdgcn_global_load_lds(
      (const __attribute__((address_space(1))) void*)g,
      (__attribute__((address_space(3))) void*)lds_dst, 16, 0, 0);
}
// barrier: LDS-writes visible, but vmem prefetches stay in flight (no vmcnt drain)
#define ENDSTEP() do {                                           \
    asm volatile("s_waitcnt lgkmcnt(0)" ::: "memory");           \
    __builtin_amdgcn_s_barrier();                                \
    __builtin_amdgcn_sched_barrier(0);                           \
  } while (0)

// ---------------- K1: rmsnorm + residual copy + fp32 gate + top4 ----------------
__global__ __launch_bounds__(256) void k_norm_gate(
    const float* __restrict__ x, const float* __restrict__ norm_w,
    const float* __restrict__ gate_w, const float* __restrict__ gate_b,
    float* __restrict__ out, unsigned short* __restrict__ t_out,
    int* __restrict__ topk_id, float* __restrict__ topk_w,
    int* __restrict__ counts)
{
  int t = blockIdx.x, tid = threadIdx.x;
  const float4* xr = (const float4*)(x + (size_t)t * H_DIM);
  float4* outr = (float4*)(out + (size_t)t * H_DIM);
  float4 xa[3];
  float ss = 0.f;
  int j = 0;
  for (int i = tid; i < 720; i += 256, j++) {
    float4 v = xr[i]; xa[j] = v; outr[i] = v;    // residual: out = x
    ss += v.x * v.x + v.y * v.y + v.z * v.z + v.w * v.w;
  }
#pragma unroll
  for (int o = 1; o < 64; o <<= 1) ss += __shfl_xor(ss, o, 64);
  __shared__ float red[4];
  if ((tid & 63) == 0) red[tid >> 6] = ss;
  __syncthreads();
  float rs = rsqrtf((red[0] + red[1] + red[2] + red[3]) * (1.f / H_DIM) + EPS_RMS);

  float part[16];
#pragma unroll
  for (int q = 0; q < 16; q++) part[q] = 0.f;
  j = 0;
  for (int i = tid; i < 720; i += 256, j++) {
    float4 v = xa[j];
    float4 w = ((const float4*)norm_w)[i];
    float t0 = v.x * rs * w.x, t1 = v.y * rs * w.y;
    float t2 = v.z * rs * w.z, t3 = v.w * rs * w.w;
    ushort4 b; b.x = f2bf(t0); b.y = f2bf(t1); b.z = f2bf(t2); b.w = f2bf(t3);
    ((ushort4*)(t_out + (size_t)t * H_DIM))[i] = b;
#pragma unroll
    for (int q = 0; q < 16; q++) {    // fp32 logits (selection accuracy)
      float4 g = ((const float4*)(gate_w + (size_t)q * H_DIM))[i];
      part[q] += t0 * g.x + t1 * g.y + t2 * g.z + t3 * g.w;
    }
  }
  __shared__ float lg[4][16];
#pragma unroll
  for (int q = 0; q < 16; q++) {
    float p = part[q];
#pragma unroll
    for (int o = 1; o < 64; o <<= 1) p += __shfl_xor(p, o, 64);
    if ((tid & 63) == 0) lg[tid >> 6][q] = p;
  }
  __syncthreads();
  if (tid == 0) {
    float logit[16];
    for (int q = 0; q < 16; q++)
      logit[q] = lg[0][q] + lg[1][q] + lg[2][q] + lg[3][q] + gate_b[q];
    unsigned used = 0; int idx[4]; float val[4];
    for (int k = 0; k < 4; k++) {           // ties -> lowest index
      float best = -3.4e38f; int bi = 0;
      for (int q = 0; q < 16; q++)
        if (!((used >> q) & 1u) && logit[q] > best) { best = logit[q]; bi = q; }
      used |= 1u << bi; idx[k] = bi; val[k] = best;
    }
    float s0 = 0.f, w4[4];
    for (int k = 0; k < 4; k++) { w4[k] = expf(val[k] - val[0]); s0 += w4[k]; }
    for (int k = 0; k < 4; k++) {
      topk_id[t * 4 + k] = idx[k];
      topk_w[t * 4 + k] = w4[k] / s0;
      atomicAdd(&counts[idx[k]], 1);
    }
  }
}

// ---------------- K2a: padded prefix offsets ----------------
__global__ void k_offsets(const int* __restrict__ counts, int* __restrict__ d_off) {
  if (threadIdx.x == 0) {
    int acc = 0;
    for (int q = 0; q < 16; q++) {
      d_off[q] = acc;
      acc += ((counts[q] + PADM - 1) / PADM) * PADM;
    }
    d_off[16] = acc;
  }
}

// ---------------- K2b: deterministic token-ordered routing lists ----------------
__global__ __launch_bounds__(256) void k_fill(
    const int* __restrict__ topk_id, const float* __restrict__ topk_w,
    const int* __restrict__ counts, const int* __restrict__ d_off,
    int* __restrict__ perm_tok, float* __restrict__ perm_w)
{
  int e = blockIdx.x;
  int base = d_off[e], pe = d_off[e + 1] - base, cnt = counts[e];
  int tid = threadIdx.x, lane = tid & 63, wv = tid >> 6;
  __shared__ int wsum[4];
  int pos = 0;
  for (int c0 = 0; c0 < T_TOK; c0 += 256) {
    int tok = c0 + tid;
    int4 ids = ((const int4*)topk_id)[tok];
    int flag = 0, slot = 0;
    if (ids.x == e) { flag = 1; slot = 0; }
    else if (ids.y == e) { flag = 1; slot = 1; }
    else if (ids.z == e) { flag = 1; slot = 2; }
    else if (ids.w == e) { flag = 1; slot = 3; }
    unsigned long long b = __ballot(flag);
    int wprefix = __popcll(b & ((1ULL << lane) - 1ULL));
    if (lane == 0) wsum[wv] = __popcll(b);
    __syncthreads();
    int woff = 0;
    for (int i = 0; i < wv; i++) woff += wsum[i];
    int tot = wsum[0] + wsum[1] + wsum[2] + wsum[3];
    if (flag) {
      int p = base + pos + woff + wprefix;
      perm_tok[p] = tok;
      perm_w[p] = topk_w[tok * 4 + slot];
    }
    pos += tot;
    __syncthreads();
  }
  for (int i = cnt + tid; i < pe; i += 256) {   // padding rows: token 0, weight 0
    perm_tok[base + i] = 0;
    perm_w[base + i] = 0.f;
  }
}

// ---- shared GEMM macros (3-buf pipeline) ----
#define STAGE_A(dstbuf, ktn) do {                                             \
  _Pragma("unroll")                                                           \
  for (int i = 0; i < 3; i++)                                                 \
    gl_lds16(aptr[i] + (size_t)(ktn) * BK, lds + (dstbuf) * ABUF + adst[i]);  \
} while (0)

#define LOAD_B(set, ktn) do {                                                 \
  _Pragma("unroll")                                                           \
  for (int j = 0; j < 3; j++) {                                               \
    set[j][0] = bptr[j][(ktn) * 8];                                           \
    set[j][1] = bptr[j][(ktn) * 8 + 1];                                       \
  }                                                                           \
} while (0)

#define PACK_B(set, dstbuf) do {                                              \
  _Pragma("unroll")                                                           \
  for (int j = 0; j < 3; j++) {                                               \
    uint4 p;                                                                  \
    p.x = pk2(set[j][0].x, set[j][0].y); p.y = pk2(set[j][0].z, set[j][0].w); \
    p.z = pk2(set[j][1].x, set[j][1].y); p.w = pk2(set[j][1].z, set[j][1].w); \
    *(uint4*)(lds + BOFF + (dstbuf) * BBUF + bdst[j]) = p;                    \
  }                                                                           \
} while (0)

#define COMPUTE(cb) do {                                                      \
  const unsigned char* Abase = lds + (cb) * ABUF + abase_off;                 \
  const unsigned char* Bbase = lds + BOFF + (cb) * BBUF + bbase_off;          \
  short8 a0 = *(const short8*)(Abase);                                        \
  short8 a1 = *(const short8*)(Abase + 1024);                                 \
  short8 a2 = *(const short8*)(Abase + 2048);                                 \
  __builtin_amdgcn_s_setprio(1);                                              \
  _Pragma("unroll")                                                           \
  for (int n = 0; n < 12; n++) {                                              \
    short8 b = *(const short8*)(Bbase + n * 1024);                            \
    acc[0][n] = __builtin_amdgcn_mfma_f32_16x16x32_bf16(a0, b, acc[0][n], 0, 0, 0); \
    acc[1][n] = __builtin_amdgcn_mfma_f32_16x16x32_bf16(a1, b, acc[1][n], 0, 0, 0); \
    acc[2][n] = __builtin_amdgcn_mfma_f32_16x16x32_bf16(a2, b, acc[2][n], 0, 0, 0); \
  }                                                                           \
  __builtin_amdgcn_s_setprio(0);                                              \
} while (0)

// main pipelined loop, shared by both GEMMs (expects lds/aptr/bptr/adst/bdst/
// abase_off/bbase_off/acc/bv0/bv1 in scope)
#define GEMM_PIPE() do {                                                      \
  /* prologue: stage tiles 0,1; pack B(0) */                                  \
  STAGE_A(0, 0); LOAD_B(bv0, 0);                                              \
  STAGE_A(1, 1); LOAD_B(bv1, 1);                                              \
  PACK_B(bv0, 0);                                                             \
  ENDSTEP();                                                                  \
  int c0 = 0;                                                                 \
  _Pragma("unroll 1")                                                         \
  for (int u = 0; u < NK / 2; u++) {                                          \
    int kt0 = 2 * u;                                                          \
    int c1 = c0 + 1; if (c1 >= 3) c1 -= 3;                                    \
    int c2 = c0 + 2; if (c2 >= 3) c2 -= 3;                                    \
    if (kt0 + 2 < NK) { STAGE_A(c2, kt0 + 2); LOAD_B(bv0, kt0 + 2); }         \
    COMPUTE(c0);                                                              \
    PACK_B(bv1, c1);                                                          \
    ENDSTEP();                                                                \
    if (kt0 + 3 < NK) { STAGE_A(c0, kt0 + 3); LOAD_B(bv1, kt0 + 3); }         \
    COMPUTE(c1);                                                              \
    if (kt0 + 2 < NK) PACK_B(bv0, c2);                                        \
    ENDSTEP();                                                                \
    c0 = c2;                                                                  \
  }                                                                           \
} while (0)

// ================= K3: grouped gemm1 + bias + SwiGLU -> act =================
__global__ __launch_bounds__(256, 2) void k_gemm1(
    const unsigned short* __restrict__ t_bf16,
    const float* __restrict__ w1, const float* __restrict__ b1,
    const int* __restrict__ perm_tok, const int* __restrict__ d_off,
    unsigned short* __restrict__ act)
{
  __shared__ __align__(16) unsigned char lds[3 * ABUF + 3 * BBUF];  // 72 KB
  const int total = d_off[16];
  int bid = blockIdx.x;
  int wg = (bid & 7) * (G1 / 8) + (bid >> 3);   // XCD-chunked, rt fastest
  int ct = wg / MAX_RT, rt = wg % MAX_RT;
  int rowbase = rt * PADM;
  if (rowbase >= total) return;
  int e = 0;
#pragma unroll
  for (int q = 0; q < E_NUM; q++) if (d_off[q + 1] <= rowbase) e = q + 1;

  int tid = threadIdx.x, lane = tid & 63, wv = tid >> 6;
  int lr = lane & 15, ch = lane >> 4;
  unsigned swz16 = (unsigned)((ch ^ ((lr >> 1) & 3)) << 4);
  unsigned abase_off = (unsigned)(wv * 3072 + lr * 64) + swz16;
  unsigned bbase_off = (unsigned)(lr * 64) + swz16;

  // A staging: gload_lds linear dst, pre-swizzled source chunk
  const unsigned short* aptr[3]; unsigned adst[3];
#pragma unroll
  for (int i = 0; i < 3; i++) {
    int cl = tid + 256 * i;                 // 0..767
    int r = cl >> 2, c = cl & 3;
    int tok = perm_tok[rowbase + r];
    aptr[i] = t_bf16 + (size_t)tok * H_DIM + ((c ^ ((r >> 1) & 3)) * 8);
    adst[i] = (unsigned)cl * 16;
  }
  // B staging: linear fp32 source, dst-swizzled ds_write
  const float4* bptr[3]; unsigned bdst[3];
#pragma unroll
  for (int j = 0; j < 3; j++) {
    int idx = tid + 256 * j;                // 0..767
    int rr = idx >> 2, c = idx & 3;
    size_t grow = (size_t)e * (2 * H_DIM) +
                  (rr < 96 ? (size_t)(ct * 96 + rr) : (size_t)(H_DIM + ct * 96 + (rr - 96)));
    bptr[j] = (const float4*)(w1 + grow * H_DIM) + c * 2;
    bdst[j] = (unsigned)(rr * 64 + ((c ^ ((rr >> 1) & 3)) << 4));
  }

  f32x4 zero = {0.f, 0.f, 0.f, 0.f};
  f32x4 acc[3][12];
#pragma unroll
  for (int m = 0; m < 3; m++)
#pragma unroll
    for (int n = 0; n < 12; n++) acc[m][n] = zero;
  float4 bv0[3][2], bv1[3][2];

  GEMM_PIPE();

  // epilogue: bias + SwiGLU, store act bf16
  int rq = lane >> 4;
#pragma unroll
  for (int m = 0; m < 3; m++) {
    int row0 = rowbase + wv * 48 + m * 16 + rq * 4;
#pragma unroll
    for (int n = 0; n < 6; n++) {
      int col = ct * 96 + n * 16 + lr;
      float bg = b1[(size_t)e * (2 * H_DIM) + col];
      float bl = b1[(size_t)e * (2 * H_DIM) + H_DIM + col];
#pragma unroll
      for (int j = 0; j < 4; j++) {
        float g = acc[m][n][j] + bg;
        float l = acc[m][n + 6][j] + bl;
        float s = 1.f / (1.f + __expf(-ALPHA * g));
        act[(size_t)(row0 + j) * H_DIM + col] = f2bf(g * s * (l + 1.f));
      }
    }
  }
}

// ================= K4: grouped gemm2 + bias, weighted atomic scatter =================
__global__ __launch_bounds__(256, 2) void k_gemm2(
    const unsigned short* __restrict__ act,
    const float* __restrict__ w2, const float* __restrict__ b2,
    const int* __restrict__ perm_tok, const float* __restrict__ perm_w,
    const int* __restrict__ d_off,
    float* __restrict__ out)
{
  __shared__ __align__(16) unsigned char lds[3 * ABUF + 3 * BBUF];  // 72 KB
  __shared__ int stok[PADM]; __shared__ float swt[PADM];
  const int total = d_off[16];
  int bid = blockIdx.x;
  int wg = (bid & 7) * (G2 / 8) + (bid >> 3);
  int ct = wg / MAX_RT, rt = wg % MAX_RT;
  int rowbase = rt * PADM;
  if (rowbase >= total) return;
  int e = 0;
#pragma unroll
  for (int q = 0; q < E_NUM; q++) if (d_off[q + 1] <= rowbase) e = q + 1;

  int tid = threadIdx.x, lane = tid & 63, wv = tid >> 6;
  int lr = lane & 15, ch = lane >> 4;
  unsigned swz16 = (unsigned)((ch ^ ((lr >> 1) & 3)) << 4);
  unsigned abase_off = (unsigned)(wv * 3072 + lr * 64) + swz16;
  unsigned bbase_off = (unsigned)(lr * 64) + swz16;

  if (tid < PADM) { stok[tid] = perm_tok[rowbase + tid]; swt[tid] = perm_w[rowbase + tid]; }

  const unsigned short* aptr[3]; unsigned adst[3];
#pragma unroll
  for (int i = 0; i < 3; i++) {
    int cl = tid + 256 * i;
    int r = cl >> 2, c = cl & 3;
    aptr[i] = act + (size_t)(rowbase + r) * H_DIM + ((c ^ ((r >> 1) & 3)) * 8);
    adst[i] = (unsigned)cl * 16;
  }
  const float4* bptr[3]; unsigned bdst[3];
#pragma unroll
  for (int j = 0; j < 3; j++) {
    int idx = tid + 256 * j;
    int rr = idx >> 2, c = idx & 3;
    size_t grow = (size_t)e * H_DIM + (size_t)(ct * 192 + rr);
    bptr[j] = (const float4*)(w2 + grow * H_DIM) + c * 2;
    bdst[j] = (unsigned)(rr * 64 + ((c ^ ((rr >> 1) & 3)) << 4));
  }

  f32x4 zero = {0.f, 0.f, 0.f, 0.f};
  f32x4 acc[3][12];
#pragma unroll
  for (int m = 0; m < 3; m++)
#pragma unroll
    for (int n = 0; n < 12; n++) acc[m][n] = zero;
  float4 bv0[3][2], bv1[3][2];

  GEMM_PIPE();

  // epilogue: bias + weighted atomic scatter
  int rq = lane >> 4;
#pragma unroll
  for (int m = 0; m < 3; m++) {
    int rl0 = wv * 48 + m * 16 + rq * 4;
#pragma unroll
    for (int n = 0; n < 12; n++) {
      int col = ct * 192 + n * 16 + lr;
      float b2v = b2[(size_t)e * H_DIM + col];
#pragma unroll
      for (int j = 0; j < 4; j++) {
        int rl = rl0 + j;
        float w = swt[rl];
        if (w != 0.f)
          atomicAdd(out + (size_t)stok[rl] * H_DIM + col, (acc[m][n][j] + b2v) * w);
      }
    }
  }
}

// ---------------- launch ----------------
extern "C" void kernel_launch(void* const* d_in, const int* in_sizes, int n_in,
                              void* d_out, int out_size, void* d_ws, size_t ws_size,
                              hipStream_t stream)
{
  const float* x      = (const float*)d_in[0];
  const float* norm_w = (const float*)d_in[1];
  const float* gate_w = (const float*)d_in[2];
  const float* gate_b = (const float*)d_in[3];
  const float* w1     = (const float*)d_in[4];
  const float* b1     = (const float*)d_in[5];
  const float* w2     = (const float*)d_in[6];
  const float* b2     = (const float*)d_in[7];
  float* out = (float*)d_out;
  char* ws = (char*)d_ws;

  // ws layout (~138.9 MB)
  unsigned short* t_bf16  = (unsigned short*)(ws);                    // 23,592,960
  unsigned short* act     = (unsigned short*)(ws + 23592960);         // 115,015,680
  int*            topk_id = (int*)(ws + 138608640);                   // 65,536
  float*          topk_w  = (float*)(ws + 138674176);                 // 65,536
  int*            perm_tk = (int*)(ws + 138739712);                   // 79,872
  float*          perm_w  = (float*)(ws + 138819584);                 // 79,872
  int*            counts  = (int*)(ws + 138899456);                   // 64
  int*            d_off   = (int*)(ws + 138899520);                   // 68

  hipMemsetAsync(counts, 0, 64, stream);
  hipLaunchKernelGGL(k_norm_gate, dim3(T_TOK), dim3(256), 0, stream,
                     x, norm_w, gate_w, gate_b, out, t_bf16, topk_id, topk_w, counts);
  hipLaunchKernelGGL(k_offsets, dim3(1), dim3(64), 0, stream, counts, d_off);
  hipLaunchKernelGGL(k_fill, dim3(16), dim3(256), 0, stream,
                     topk_id, topk_w, counts, d_off, perm_tk, perm_w);
  hipLaunchKernelGGL(k_gemm1, dim3(G1), dim3(256), 0, stream,
                     t_bf16, w1, b1, perm_tk, d_off, act);
  hipLaunchKernelGGL(k_gemm2, dim3(G2), dim3(256), 0, stream,
                     act, w2, b2, perm_tk, perm_w, d_off, out);
}

// Round 5
// 1572.800 us; speedup vs baseline: 1.8273x; 1.8273x over previous
//
#include <hip/hip_runtime.h>
#include <hip/hip_bf16.h>
#include <math.h>
#include <stdint.h>

// Problem constants
#define T_TOK 4096
#define H_DIM 2880
#define E_NUM 16
#define ALPHA 1.702f
#define EPS_RMS 1e-5f

// GEMM tiling: BM=192 (4 waves x 3 m-frags), BN=192 effective, BK=32.
// A: 3-buffer LDS (depth-2 prefetch, register-free via global_load_lds).
// B: 2-buffer LDS, depth-1 register prefetch (single bv set = 24 VGPR).
// Barrier = lgkmcnt(0) + s_barrier only; NO vmcnt(0) in the main loop.
#define PADM 192
#define BK 32
#define NK (H_DIM / BK)       // 90 (even)
#define MAX_RT 104
#define NCT1 30               // gemm1 col tiles of 96 (+96 lin)
#define NCT2 15               // gemm2 col tiles of 192
#define G1 (MAX_RT * NCT1)    // 3120 (div 8)
#define G2 (MAX_RT * NCT2)    // 1560 (div 8)
#define ABUF 12288            // A buffer: 192 rows x 64 B  (x3)
#define BBUF 12288            // B buffer: 192 rows x 64 B  (x2)
#define BOFF 36864            // B region base; total LDS 60 KB

typedef __attribute__((ext_vector_type(8))) short short8;
typedef __attribute__((ext_vector_type(4))) float f32x4;

__device__ __forceinline__ unsigned short f2bf(float f) {
  unsigned u = __float_as_uint(f);
  return (unsigned short)((u + 0x7fffu + ((u >> 16) & 1u)) >> 16);
}
// packed f32x2 -> bf16x2 in one VALU inst (RNE), lo=a hi=b
__device__ __forceinline__ unsigned cpk(float a, float b) {
  unsigned r;
  asm("v_cvt_pk_bf16_f32 %0, %1, %2" : "=v"(r) : "v"(a), "v"(b));
  return r;
}
__device__ __forceinline__ void gl_lds16(const void* g, unsigned char* lds_dst) {
  __builtin_amdgcn_global_load_lds(
      (const __attribute__((address_space(1))) void*)g,
      (__attribute__((address_space(3))) void*)lds_dst, 16, 0, 0);
}
// end-of-step barrier: LDS writes visible; vmem prefetches stay in flight
#define ENDSTEP() do {                                           \
    asm volatile("s_waitcnt lgkmcnt(0)" ::: "memory");           \
    __builtin_amdgcn_s_barrier();                                \
    __builtin_amdgcn_sched_barrier(0);                           \
  } while (0)

// ---------------- K1: rmsnorm + residual copy + fp32 gate + top4 ----------------
__global__ __launch_bounds__(256) void k_norm_gate(
    const float* __restrict__ x, const float* __restrict__ norm_w,
    const float* __restrict__ gate_w, const float* __restrict__ gate_b,
    float* __restrict__ out, unsigned short* __restrict__ t_out,
    int* __restrict__ topk_id, float* __restrict__ topk_w,
    int* __restrict__ counts)
{
  int t = blockIdx.x, tid = threadIdx.x;
  const float4* xr = (const float4*)(x + (size_t)t * H_DIM);
  float4* outr = (float4*)(out + (size_t)t * H_DIM);
  float4 xa[3];
  float ss = 0.f;
  int j = 0;
  for (int i = tid; i < 720; i += 256, j++) {
    float4 v = xr[i]; xa[j] = v; outr[i] = v;    // residual: out = x
    ss += v.x * v.x + v.y * v.y + v.z * v.z + v.w * v.w;
  }
#pragma unroll
  for (int o = 1; o < 64; o <<= 1) ss += __shfl_xor(ss, o, 64);
  __shared__ float red[4];
  if ((tid & 63) == 0) red[tid >> 6] = ss;
  __syncthreads();
  float rs = rsqrtf((red[0] + red[1] + red[2] + red[3]) * (1.f / H_DIM) + EPS_RMS);

  float part[16];
#pragma unroll
  for (int q = 0; q < 16; q++) part[q] = 0.f;
  j = 0;
  for (int i = tid; i < 720; i += 256, j++) {
    float4 v = xa[j];
    float4 w = ((const float4*)norm_w)[i];
    float t0 = v.x * rs * w.x, t1 = v.y * rs * w.y;
    float t2 = v.z * rs * w.z, t3 = v.w * rs * w.w;
    ushort4 b; b.x = f2bf(t0); b.y = f2bf(t1); b.z = f2bf(t2); b.w = f2bf(t3);
    ((ushort4*)(t_out + (size_t)t * H_DIM))[i] = b;
#pragma unroll
    for (int q = 0; q < 16; q++) {    // fp32 logits (selection accuracy)
      float4 g = ((const float4*)(gate_w + (size_t)q * H_DIM))[i];
      part[q] += t0 * g.x + t1 * g.y + t2 * g.z + t3 * g.w;
    }
  }
  __shared__ float lg[4][16];
#pragma unroll
  for (int q = 0; q < 16; q++) {
    float p = part[q];
#pragma unroll
    for (int o = 1; o < 64; o <<= 1) p += __shfl_xor(p, o, 64);
    if ((tid & 63) == 0) lg[tid >> 6][q] = p;
  }
  __syncthreads();
  if (tid == 0) {
    float logit[16];
    for (int q = 0; q < 16; q++)
      logit[q] = lg[0][q] + lg[1][q] + lg[2][q] + lg[3][q] + gate_b[q];
    unsigned used = 0; int idx[4]; float val[4];
    for (int k = 0; k < 4; k++) {           // ties -> lowest index
      float best = -3.4e38f; int bi = 0;
      for (int q = 0; q < 16; q++)
        if (!((used >> q) & 1u) && logit[q] > best) { best = logit[q]; bi = q; }
      used |= 1u << bi; idx[k] = bi; val[k] = best;
    }
    float s0 = 0.f, w4[4];
    for (int k = 0; k < 4; k++) { w4[k] = expf(val[k] - val[0]); s0 += w4[k]; }
    for (int k = 0; k < 4; k++) {
      topk_id[t * 4 + k] = idx[k];
      topk_w[t * 4 + k] = w4[k] / s0;
      atomicAdd(&counts[idx[k]], 1);
    }
  }
}

// ---------------- K2a: padded prefix offsets ----------------
__global__ void k_offsets(const int* __restrict__ counts, int* __restrict__ d_off) {
  if (threadIdx.x == 0) {
    int acc = 0;
    for (int q = 0; q < 16; q++) {
      d_off[q] = acc;
      acc += ((counts[q] + PADM - 1) / PADM) * PADM;
    }
    d_off[16] = acc;
  }
}

// ---------------- K2b: deterministic token-ordered routing lists ----------------
__global__ __launch_bounds__(256) void k_fill(
    const int* __restrict__ topk_id, const float* __restrict__ topk_w,
    const int* __restrict__ counts, const int* __restrict__ d_off,
    int* __restrict__ perm_tok, float* __restrict__ perm_w)
{
  int e = blockIdx.x;
  int base = d_off[e], pe = d_off[e + 1] - base, cnt = counts[e];
  int tid = threadIdx.x, lane = tid & 63, wv = tid >> 6;
  __shared__ int wsum[4];
  int pos = 0;
  for (int c0 = 0; c0 < T_TOK; c0 += 256) {
    int tok = c0 + tid;
    int4 ids = ((const int4*)topk_id)[tok];
    int flag = 0, slot = 0;
    if (ids.x == e) { flag = 1; slot = 0; }
    else if (ids.y == e) { flag = 1; slot = 1; }
    else if (ids.z == e) { flag = 1; slot = 2; }
    else if (ids.w == e) { flag = 1; slot = 3; }
    unsigned long long b = __ballot(flag);
    int wprefix = __popcll(b & ((1ULL << lane) - 1ULL));
    if (lane == 0) wsum[wv] = __popcll(b);
    __syncthreads();
    int woff = 0;
    for (int i = 0; i < wv; i++) woff += wsum[i];
    int tot = wsum[0] + wsum[1] + wsum[2] + wsum[3];
    if (flag) {
      int p = base + pos + woff + wprefix;
      perm_tok[p] = tok;
      perm_w[p] = topk_w[tok * 4 + slot];
    }
    pos += tot;
    __syncthreads();
  }
  for (int i = cnt + tid; i < pe; i += 256) {   // padding rows: token 0, weight 0
    perm_tok[base + i] = 0;
    perm_w[base + i] = 0.f;
  }
}

// ---- shared GEMM macros ----
#define STAGE_A(abuf, ktn) do {                                               \
  _Pragma("unroll")                                                           \
  for (int i = 0; i < 3; i++)                                                 \
    gl_lds16(aptr[i] + (size_t)(ktn) * BK, lds + (abuf) * ABUF + adst[i]);    \
} while (0)

#define LOAD_B(ktn) do {                                                      \
  _Pragma("unroll")                                                           \
  for (int j = 0; j < 3; j++) {                                               \
    bv[j][0] = bptr[j][(ktn) * 8];                                            \
    bv[j][1] = bptr[j][(ktn) * 8 + 1];                                        \
  }                                                                           \
} while (0)

#define PACK_B(bbuf) do {                                                     \
  _Pragma("unroll")                                                           \
  for (int j = 0; j < 3; j++) {                                               \
    uint4 p;                                                                  \
    p.x = cpk(bv[j][0].x, bv[j][0].y); p.y = cpk(bv[j][0].z, bv[j][0].w);     \
    p.z = cpk(bv[j][1].x, bv[j][1].y); p.w = cpk(bv[j][1].z, bv[j][1].w);     \
    *(uint4*)(lds + BOFF + (bbuf) * BBUF + bdst[j]) = p;                      \
  }                                                                           \
} while (0)

#define COMPUTE(abuf, bbuf) do {                                              \
  const unsigned char* Abase = lds + (abuf) * ABUF + abase_off;               \
  const unsigned char* Bbase = lds + BOFF + (bbuf) * BBUF + bbase_off;        \
  short8 a0 = *(const short8*)(Abase);                                        \
  short8 a1 = *(const short8*)(Abase + 1024);                                 \
  short8 a2 = *(const short8*)(Abase + 2048);                                 \
  __builtin_amdgcn_s_setprio(1);                                              \
  _Pragma("unroll")                                                           \
  for (int n = 0; n < 12; n++) {                                              \
    short8 b = *(const short8*)(Bbase + n * 1024);                            \
    acc[0][n] = __builtin_amdgcn_mfma_f32_16x16x32_bf16(a0, b, acc[0][n], 0, 0, 0); \
    acc[1][n] = __builtin_amdgcn_mfma_f32_16x16x32_bf16(a1, b, acc[1][n], 0, 0, 0); \
    acc[2][n] = __builtin_amdgcn_mfma_f32_16x16x32_bf16(a2, b, acc[2][n], 0, 0, 0); \
  }                                                                           \
  __builtin_amdgcn_s_setprio(0);                                              \
} while (0)

// Pipeline:
//  step kt: LOAD_B(kt+1); STAGE_A((kt+2)%3, kt+2); COMPUTE(kt%3, kt&1);
//           PACK_B((kt+1)&1)  [data-dep waits B(kt+1); in-order vmcnt =>
//           A(kt+1) (issued step kt-1, before B(kt+1)) has landed];
//           lgkmcnt(0); s_barrier.   A(kt+2) stays in flight across barrier.
#define GEMM_PIPE() do {                                                      \
  STAGE_A(0, 0); STAGE_A(1, 1); LOAD_B(0);                                    \
  PACK_B(0);               /* waits B(0) => A(0),A(1) issued earlier? A(0),A(1) before B(0): yes */ \
  ENDSTEP();                                                                  \
  int ca = 0;                                                                 \
  _Pragma("unroll 1")                                                         \
  for (int u = 0; u < NK / 2; u++) {                                          \
    int kt = 2 * u;                                                           \
    int ca1 = ca + 1; if (ca1 >= 3) ca1 -= 3;                                 \
    int ca2 = ca + 2; if (ca2 >= 3) ca2 -= 3;                                 \
    if (kt + 1 < NK) LOAD_B(kt + 1);                                          \
    if (kt + 2 < NK) STAGE_A(ca2, kt + 2);                                    \
    COMPUTE(ca, 0);                                                           \
    if (kt + 1 < NK) PACK_B(1);                                               \
    ENDSTEP();                                                                \
    if (kt + 2 < NK) LOAD_B(kt + 2);                                          \
    if (kt + 3 < NK) STAGE_A(ca, kt + 3);                                     \
    COMPUTE(ca1, 1);                                                          \
    if (kt + 2 < NK) PACK_B(0);                                               \
    ENDSTEP();                                                                \
    ca = ca2;                                                                 \
  }                                                                           \
} while (0)

// ================= K3: grouped gemm1 + bias + SwiGLU -> act =================
__global__ __launch_bounds__(256, 2) void k_gemm1(
    const unsigned short* __restrict__ t_bf16,
    const float* __restrict__ w1, const float* __restrict__ b1,
    const int* __restrict__ perm_tok, const int* __restrict__ d_off,
    unsigned short* __restrict__ act)
{
  __shared__ __align__(16) unsigned char lds[3 * ABUF + 2 * BBUF];  // 60 KB
  const int total = d_off[16];
  int bid = blockIdx.x;
  int wg = (bid & 7) * (G1 / 8) + (bid >> 3);   // XCD-chunked, rt fastest
  int ct = wg / MAX_RT, rt = wg % MAX_RT;
  int rowbase = rt * PADM;
  if (rowbase >= total) return;
  int e = 0;
#pragma unroll
  for (int q = 0; q < E_NUM; q++) if (d_off[q + 1] <= rowbase) e = q + 1;

  int tid = threadIdx.x, lane = tid & 63, wv = tid >> 6;
  int lr = lane & 15, ch = lane >> 4;
  unsigned swz16 = (unsigned)((ch ^ ((lr >> 1) & 3)) << 4);
  unsigned abase_off = (unsigned)(wv * 3072 + lr * 64) + swz16;
  unsigned bbase_off = (unsigned)(lr * 64) + swz16;

  // A staging: gload_lds linear dst, pre-swizzled source chunk
  const unsigned short* aptr[3]; unsigned adst[3];
#pragma unroll
  for (int i = 0; i < 3; i++) {
    int cl = tid + 256 * i;                 // 0..767
    int r = cl >> 2, c = cl & 3;
    int tok = perm_tok[rowbase + r];
    aptr[i] = t_bf16 + (size_t)tok * H_DIM + ((c ^ ((r >> 1) & 3)) * 8);
    adst[i] = (unsigned)cl * 16;
  }
  // B staging: linear fp32 source, dst-swizzled ds_write
  const float4* bptr[3]; unsigned bdst[3];
#pragma unroll
  for (int j = 0; j < 3; j++) {
    int idx = tid + 256 * j;                // 0..767
    int rr = idx >> 2, c = idx & 3;
    size_t grow = (size_t)e * (2 * H_DIM) +
                  (rr < 96 ? (size_t)(ct * 96 + rr) : (size_t)(H_DIM + ct * 96 + (rr - 96)));
    bptr[j] = (const float4*)(w1 + grow * H_DIM) + c * 2;
    bdst[j] = (unsigned)(rr * 64 + ((c ^ ((rr >> 1) & 3)) << 4));
  }

  f32x4 zero = {0.f, 0.f, 0.f, 0.f};
  f32x4 acc[3][12];
#pragma unroll
  for (int m = 0; m < 3; m++)
#pragma unroll
    for (int n = 0; n < 12; n++) acc[m][n] = zero;
  float4 bv[3][2];

  GEMM_PIPE();

  // epilogue: bias + SwiGLU, store act bf16
  int rq = lane >> 4;
#pragma unroll
  for (int m = 0; m < 3; m++) {
    int row0 = rowbase + wv * 48 + m * 16 + rq * 4;
#pragma unroll
    for (int n = 0; n < 6; n++) {
      int col = ct * 96 + n * 16 + lr;
      float bg = b1[(size_t)e * (2 * H_DIM) + col];
      float bl = b1[(size_t)e * (2 * H_DIM) + H_DIM + col];
#pragma unroll
      for (int j = 0; j < 4; j++) {
        float g = acc[m][n][j] + bg;
        float l = acc[m][n + 6][j] + bl;
        float s = 1.f / (1.f + __expf(-ALPHA * g));
        act[(size_t)(row0 + j) * H_DIM + col] = f2bf(g * s * (l + 1.f));
      }
    }
  }
}

// ================= K4: grouped gemm2 + bias, weighted atomic scatter =================
__global__ __launch_bounds__(256, 2) void k_gemm2(
    const unsigned short* __restrict__ act,
    const float* __restrict__ w2, const float* __restrict__ b2,
    const int* __restrict__ perm_tok, const float* __restrict__ perm_w,
    const int* __restrict__ d_off,
    float* __restrict__ out)
{
  __shared__ __align__(16) unsigned char lds[3 * ABUF + 2 * BBUF];  // 60 KB
  __shared__ int stok[PADM]; __shared__ float swt[PADM];
  const int total = d_off[16];
  int bid = blockIdx.x;
  int wg = (bid & 7) * (G2 / 8) + (bid >> 3);
  int ct = wg / MAX_RT, rt = wg % MAX_RT;
  int rowbase = rt * PADM;
  if (rowbase >= total) return;
  int e = 0;
#pragma unroll
  for (int q = 0; q < E_NUM; q++) if (d_off[q + 1] <= rowbase) e = q + 1;

  int tid = threadIdx.x, lane = tid & 63, wv = tid >> 6;
  int lr = lane & 15, ch = lane >> 4;
  unsigned swz16 = (unsigned)((ch ^ ((lr >> 1) & 3)) << 4);
  unsigned abase_off = (unsigned)(wv * 3072 + lr * 64) + swz16;
  unsigned bbase_off = (unsigned)(lr * 64) + swz16;

  if (tid < PADM) { stok[tid] = perm_tok[rowbase + tid]; swt[tid] = perm_w[rowbase + tid]; }

  const unsigned short* aptr[3]; unsigned adst[3];
#pragma unroll
  for (int i = 0; i < 3; i++) {
    int cl = tid + 256 * i;
    int r = cl >> 2, c = cl & 3;
    aptr[i] = act + (size_t)(rowbase + r) * H_DIM + ((c ^ ((r >> 1) & 3)) * 8);
    adst[i] = (unsigned)cl * 16;
  }
  const float4* bptr[3]; unsigned bdst[3];
#pragma unroll
  for (int j = 0; j < 3; j++) {
    int idx = tid + 256 * j;
    int rr = idx >> 2, c = idx & 3;
    size_t grow = (size_t)e * H_DIM + (size_t)(ct * 192 + rr);
    bptr[j] = (const float4*)(w2 + grow * H_DIM) + c * 2;
    bdst[j] = (unsigned)(rr * 64 + ((c ^ ((rr >> 1) & 3)) << 4));
  }

  f32x4 zero = {0.f, 0.f, 0.f, 0.f};
  f32x4 acc[3][12];
#pragma unroll
  for (int m = 0; m < 3; m++)
#pragma unroll
    for (int n = 0; n < 12; n++) acc[m][n] = zero;
  float4 bv[3][2];

  GEMM_PIPE();

  // epilogue: bias + weighted atomic scatter
  int rq = lane >> 4;
#pragma unroll
  for (int m = 0; m < 3; m++) {
    int rl0 = wv * 48 + m * 16 + rq * 4;
#pragma unroll
    for (int n = 0; n < 12; n++) {
      int col = ct * 192 + n * 16 + lr;
      float b2v = b2[(size_t)e * H_DIM + col];
#pragma unroll
      for (int j = 0; j < 4; j++) {
        int rl = rl0 + j;
        float w = swt[rl];
        if (w != 0.f)
          atomicAdd(out + (size_t)stok[rl] * H_DIM + col, (acc[m][n][j] + b2v) * w);
      }
    }
  }
}

// ---------------- launch ----------------
extern "C" void kernel_launch(void* const* d_in, const int* in_sizes, int n_in,
                              void* d_out, int out_size, void* d_ws, size_t ws_size,
                              hipStream_t stream)
{
  const float* x      = (const float*)d_in[0];
  const float* norm_w = (const float*)d_in[1];
  const float* gate_w = (const float*)d_in[2];
  const float* gate_b = (const float*)d_in[3];
  const float* w1     = (const float*)d_in[4];
  const float* b1     = (const float*)d_in[5];
  const float* w2     = (const float*)d_in[6];
  const float* b2     = (const float*)d_in[7];
  float* out = (float*)d_out;
  char* ws = (char*)d_ws;

  // ws layout (~138.9 MB)
  unsigned short* t_bf16  = (unsigned short*)(ws);                    // 23,592,960
  unsigned short* act     = (unsigned short*)(ws + 23592960);         // 115,015,680
  int*            topk_id = (int*)(ws + 138608640);                   // 65,536
  float*          topk_w  = (float*)(ws + 138674176);                 // 65,536
  int*            perm_tk = (int*)(ws + 138739712);                   // 79,872
  float*          perm_w  = (float*)(ws + 138819584);                 // 79,872
  int*            counts  = (int*)(ws + 138899456);                   // 64
  int*            d_off   = (int*)(ws + 138899520);                   // 68

  hipMemsetAsync(counts, 0, 64, stream);
  hipLaunchKernelGGL(k_norm_gate, dim3(T_TOK), dim3(256), 0, stream,
                     x, norm_w, gate_w, gate_b, out, t_bf16, topk_id, topk_w, counts);
  hipLaunchKernelGGL(k_offsets, dim3(1), dim3(64), 0, stream, counts, d_off);
  hipLaunchKernelGGL(k_fill, dim3(16), dim3(256), 0, stream,
                     topk_id, topk_w, counts, d_off, perm_tk, perm_w);
  hipLaunchKernelGGL(k_gemm1, dim3(G1), dim3(256), 0, stream,
                     t_bf16, w1, b1, perm_tk, d_off, act);
  hipLaunchKernelGGL(k_gemm2, dim3(G2), dim3(256), 0, stream,
                     act, w2, b2, perm_tk, perm_w, d_off, out);
}